// Round 7
// baseline (1464.095 us; speedup 1.0000x reference)
//
#include <hip/hip_runtime.h>

// EMA chunked scan + inverse-gather broadcast for DeChunkLayer (R7).
// SINGLE fused kernel + one tiny memset node.
//
// x: (1, 16384, 1024) f32, p_selected: (16384,) f32, b: (1, 32768) i32
// out: (1, 32768, 1024) f32
// z_t = (1-p_t) z_{t-1} + p_t x_t  (p clipped to [1e-4, 1-1e-4])
// out[f] = z[t] for f in [pos[t], pos[t+1])
//
// R7 rationale: R4 vs R6 identical-code repro (226.1 vs 225.9) shows tight
// measurement; launch boundaries (~4-5 us each) and the K2 x re-read are the
// remaining levers. One kernel, 512 blocks:
//   ticket -> chunk id (started-order => deadlock-free waits, no dispatch-order
//   assumption); local scan retaining 32 states in regs (x read ONCE);
//   publish aggregate (threadfence + device-scope release flag); pos from raw
//   b per block (no cross-block dep); replay predecessors' aggregates
//   (flag-guarded, batch-16, L2); out[t] = hl[t] + (prod a)*carry.

#define DCH 1024
#define L_COMP 16384
#define L_FULL 32768
#define CHUNK 32
#define NCHUNK (L_COMP / CHUNK)   // 512
#define EPSV 1e-4f

typedef float v4f __attribute__((ext_vector_type(4)));

__device__ __forceinline__ float clipp(float p) {
    p = fmaxf(p, EPSV);
    return fminf(p, 1.0f - EPSV);
}

__global__ __launch_bounds__(256, 2) void fused_kernel(
    const float* __restrict__ x, const float* __restrict__ p,
    const int* __restrict__ b, float* __restrict__ out,
    int* __restrict__ ticket, int* __restrict__ flags,
    float* __restrict__ Abuf, float* __restrict__ Bbuf) {

    const int tid = threadIdx.x;
    const int lane = tid & 63;
    const int wave = tid >> 6;

    __shared__ int s_c;
    if (tid == 0) s_c = atomicAdd(ticket, 1);
    __syncthreads();
    const int c = s_c;          // my chunk (started-order)
    const int base = c * CHUNK;

    __shared__ int sp[257];
    __shared__ int spos[CHUNK + 1];
    __shared__ int wtot[4];
    __shared__ float spv[CHUNK];

    // ---- Phase 1: local chunk scan (zero init), retain all 32 states in regs
    v4f hl[CHUNK];
    {
        const v4f* x4 = reinterpret_cast<const v4f*>(x) + (size_t)base * (DCH / 4) + tid;
        v4f h = (v4f)0.f;
#pragma unroll
        for (int ib = 0; ib < CHUNK; ib += 8) {
            v4f xv[8];
            float pv[8];
#pragma unroll
            for (int j = 0; j < 8; ++j) {
                xv[j] = x4[(ib + j) * (DCH / 4)];
                pv[j] = clipp(p[base + ib + j]); // uniform -> scalar load
            }
#pragma unroll
            for (int j = 0; j < 8; ++j) {
                float a = 1.0f - pv[j];
                h = a * h + pv[j] * xv[j];
                hl[ib + j] = h;
            }
        }
    }
    if (tid < CHUNK) spv[tid] = clipp(p[base + tid]);
    __syncthreads();

    // ---- Phase 2: publish aggregate (B_c = hl[31], A_c = prod(1-p)), release flag
    reinterpret_cast<v4f*>(Bbuf)[c * (DCH / 4) + tid] = hl[CHUNK - 1];
    if (tid == 0) {
        float ap = 1.0f;
#pragma unroll
        for (int t = 0; t < CHUNK; ++t) ap *= (1.0f - spv[t]);
        Abuf[c] = ap;
    }
    __threadfence();   // release this thread's Bbuf/Abuf stores to device scope
    __syncthreads();   // all threads fenced before the flag is set
    if (tid == 0)
        __hip_atomic_store(&flags[c], 1, __ATOMIC_RELEASE, __HIP_MEMORY_SCOPE_AGENT);

    // ---- Phase 3: pos rank-select from raw b (no cross-block dependency)
    {
        const int4* b4 = reinterpret_cast<const int4*>(b) + tid * 32; // 128 elems/thread
        int s = 0;
        for (int q = 0; q < 32; ++q) {
            int4 w = b4[q];
            s += w.x + w.y + w.z + w.w;
        }
        int incl = s;
#pragma unroll
        for (int off = 1; off < 64; off <<= 1) {
            int n = __shfl_up(incl, off, 64);
            if (lane >= off) incl += n;
        }
        if (lane == 63) wtot[wave] = incl;
        __syncthreads();
        int woff = 0;
        for (int w = 0; w < wave; ++w) woff += wtot[w];
        sp[tid] = woff + incl - s; // ones before stripe tid (exclusive)
        if (tid == 0) sp[256] = L_COMP;
        __syncthreads();
        if (tid <= CHUNK) {
            int r = base + tid; // global one-rank (0-indexed)
            int posv = L_FULL;
            if (r < L_COMP) {
                int lo = 0, hi = 256;
                while (hi - lo > 1) {
                    int mid = (lo + hi) >> 1;
                    if (sp[mid] <= r) lo = mid; else hi = mid;
                }
                int lr = r - sp[lo];
                const int4* seg = reinterpret_cast<const int4*>(b) + lo * 32;
                int cnt = 0;
                for (int q = 0; q < 32; ++q) {
                    int4 w = seg[q];
                    if (w.x) { if (cnt == lr) posv = lo * 128 + 4 * q + 0; ++cnt; }
                    if (w.y) { if (cnt == lr) posv = lo * 128 + 4 * q + 1; ++cnt; }
                    if (w.z) { if (cnt == lr) posv = lo * 128 + 4 * q + 2; ++cnt; }
                    if (w.w) { if (cnt == lr) posv = lo * 128 + 4 * q + 3; ++cnt; }
                }
            }
            spos[tid] = posv;
        }
    }
    __syncthreads();

    // ---- Phase 4: replay predecessors' aggregates -> carry (state before chunk c)
    v4f carry = (v4f)0.f;
    {
        const v4f* B4 = reinterpret_cast<const v4f*>(Bbuf) + tid;
        int k = 0;
        for (; k + 16 <= c; k += 16) {
            bool ok;
            do {
                ok = true;
#pragma unroll
                for (int q = 0; q < 16; ++q)
                    ok = ok && (__hip_atomic_load(&flags[k + q], __ATOMIC_RELAXED,
                                                  __HIP_MEMORY_SCOPE_AGENT) != 0);
            } while (!ok);
            __threadfence(); // acquire: order aggregate loads after flag observation
            v4f bv[16];
            float av[16];
#pragma unroll
            for (int j = 0; j < 16; ++j) {
                bv[j] = B4[(k + j) * (DCH / 4)];
                av[j] = Abuf[k + j]; // uniform -> scalar load
            }
#pragma unroll
            for (int j = 0; j < 16; ++j)
                carry = av[j] * carry + bv[j];
        }
        for (; k < c; ++k) {
            while (__hip_atomic_load(&flags[k], __ATOMIC_RELAXED,
                                     __HIP_MEMORY_SCOPE_AGENT) == 0) {}
            __threadfence();
            v4f bv = B4[k * (DCH / 4)];
            carry = Abuf[k] * carry + bv;
        }
    }

    // ---- Phase 5: out[t] = hl[t] + (prod_{i<=t} a_i) * carry; ranged broadcast writes
    {
        v4f* out4 = reinterpret_cast<v4f*>(out) + tid;
        float diff = 1.0f;
        int f0 = spos[0];
#pragma unroll
        for (int t = 0; t < CHUNK; ++t) {
            diff *= (1.0f - spv[t]);
            v4f h = hl[t] + diff * carry;
            int fe = spos[t + 1];
            for (int f = f0; f < fe; ++f)
                out4[(size_t)f * (DCH / 4)] = h;
            f0 = fe;
        }
    }
}

extern "C" void kernel_launch(void* const* d_in, const int* in_sizes, int n_in,
                              void* d_out, int out_size, void* d_ws, size_t ws_size,
                              hipStream_t stream) {
    const float* x = (const float*)d_in[0];
    const float* p = (const float*)d_in[1];
    const int* b = (const int*)d_in[2];
    float* out = (float*)d_out;

    char* ws = (char*)d_ws;
    int* ticket = (int*)ws;                    // 1 int  @ 0
    int* flags = (int*)(ws + 64);              // 512 ints @ 64
    float* Abuf = (float*)(ws + 4096);         // 512 floats (not memset; flag-guarded)
    float* Bbuf = (float*)(ws + 8192);         // 512*1024 floats (2 MiB), 16B aligned

    // zero ticket+flags every launch (ws is poisoned 0xAA before each timed call)
    hipMemsetAsync(ws, 0, 4096, stream);
    fused_kernel<<<NCHUNK, 256, 0, stream>>>(x, p, b, out, ticket, flags, Abuf, Bbuf);
}

// Round 8
// 234.915 us; speedup vs baseline: 6.2325x; 6.2325x over previous
//
#include <hip/hip_runtime.h>

// EMA chunked scan + inverse-gather broadcast for DeChunkLayer (R8).
//
// x: (1, 16384, 1024) f32, p_selected: (16384,) f32, b: (1, 32768) i32
// out: (1, 32768, 1024) f32
// z_t = (1-p_t) z_{t-1} + p_t x_t  (p clipped to [1e-4, 1-1e-4])
// out[f] = z[t] for f in [pos[t], pos[t+1])
//
// Calibration from R7: harness fixed overhead ~129 us; R4/R6 kernel portion
// ~97 us vs ~40 us traffic floor. R7's intra-kernel spin-wait (agent-scope
// acquire on non-coherent XCD L2s) serialized to 1335 us — never again.
// R8 = R6 minus the per-block redundant interchunk replay (512 MB L2 reads),
// plus the tiny interchunk kernel. NO nontemporal hints (R5's regression was
// the nt x-loads forcing a 64 MiB HBM re-fetch instead of L3 hits).
//
//  K1   chunk_kernel     : per-chunk local scan -> Bbuf/Abuf; b segment sums.
//  K1.5 interchunk_kernel: 4 blocks, serial scan over 512 aggregates -> Hbuf.
//  K2   dechunk_kernel   : pos rank-select + final chunk scan (init from Hbuf)
//                          + ranged broadcast writes. Cached loads/stores.

#define DCH 1024
#define L_COMP 16384
#define L_FULL 32768
#define CHUNK 32
#define NCHUNK (L_COMP / CHUNK)   // 512
#define SEG (L_FULL / NCHUNK)     // 64 b-elements per chunk-segment
#define EPSV 1e-4f

typedef float v4f __attribute__((ext_vector_type(4)));

__device__ __forceinline__ float clipp(float p) {
    p = fmaxf(p, EPSV);
    return fminf(p, 1.0f - EPSV);
}

// ---- K1: chunk-local scan (zero init) -> Bbuf[c], Abuf[c]; b segment sums
__global__ __launch_bounds__(256, 2) void chunk_kernel(
    const float* __restrict__ x, const float* __restrict__ p,
    const int* __restrict__ b,
    float* __restrict__ Bbuf, float* __restrict__ Abuf, int* __restrict__ bsum) {
    const int c = blockIdx.x;
    const int tid = threadIdx.x;
    const int lane = tid & 63;
    const int wave = tid >> 6;
    const int base = c * CHUNK;

    const v4f* x4 = reinterpret_cast<const v4f*>(x) + (size_t)base * (DCH / 4) + tid;
    v4f h = (v4f)0.f;
    float aprod = 1.0f;
    for (int ib = 0; ib < CHUNK; ib += 8) {
        v4f xv[8];
        float pv[8];
#pragma unroll
        for (int j = 0; j < 8; ++j) {
            xv[j] = x4[(ib + j) * (DCH / 4)];
            pv[j] = clipp(p[base + ib + j]); // uniform -> scalar load
        }
#pragma unroll
        for (int j = 0; j < 8; ++j) {
            float a = 1.0f - pv[j];
            h = a * h + pv[j] * xv[j];
            aprod *= a;
        }
    }
    reinterpret_cast<v4f*>(Bbuf)[c * (DCH / 4) + tid] = h;
    if (tid == 0) Abuf[c] = aprod;
    if (wave == 0) {
        int v = b[c * SEG + lane];
        int s = v;
#pragma unroll
        for (int off = 1; off < 64; off <<= 1) s += __shfl_xor(s, off, 64);
        if (lane == 0) bsum[c] = s;
    }
}

// ---- K1.5: serial inter-chunk scan; Hbuf[k][ch] = state BEFORE chunk k.
// 4 blocks x 64 threads, one float4 channel-group per thread.
#define BATCHB 32
__global__ __launch_bounds__(64) void interchunk_kernel(
    const float* __restrict__ Bbuf, const float* __restrict__ Abuf,
    float* __restrict__ Hbuf) {
    const int ch4 = blockIdx.x * 64 + threadIdx.x; // float4 channel group (0..255)
    const v4f* B4 = reinterpret_cast<const v4f*>(Bbuf) + ch4;
    v4f* H4 = reinterpret_cast<v4f*>(Hbuf) + ch4;
    v4f h = (v4f)0.f;
    for (int cb = 0; cb < NCHUNK; cb += BATCHB) {
        v4f bv[BATCHB];
        float av[BATCHB];
#pragma unroll
        for (int j = 0; j < BATCHB; ++j) {
            bv[j] = B4[(cb + j) * (DCH / 4)];
            av[j] = Abuf[cb + j]; // uniform -> scalar load
        }
#pragma unroll
        for (int j = 0; j < BATCHB; ++j) {
            H4[(cb + j) * (DCH / 4)] = h;
            h = av[j] * h + bv[j];
        }
    }
}

// ---- K2: pos rank-select + final chunk scan (init from Hbuf) + ranged writes
__global__ __launch_bounds__(256, 2) void dechunk_kernel(
    const float* __restrict__ x, const float* __restrict__ p,
    const int* __restrict__ b, float* __restrict__ out,
    const float* __restrict__ Hbuf, const int* __restrict__ bsum) {
    const int c = blockIdx.x;
    const int tid = threadIdx.x;
    const int lane = tid & 63;
    const int wave = tid >> 6;
    const int base = c * CHUNK;

    __shared__ int bpref[NCHUNK + 1];
    __shared__ int spos[CHUNK + 1];
    __shared__ int wtot[4];

    // (a) block-local exclusive prefix over the 512 segment sums
    {
        int v0 = bsum[2 * tid];
        int v1 = bsum[2 * tid + 1];
        int s = v0 + v1;
        int incl = s;
#pragma unroll
        for (int off = 1; off < 64; off <<= 1) {
            int n = __shfl_up(incl, off, 64);
            if (lane >= off) incl += n;
        }
        if (lane == 63) wtot[wave] = incl;
        __syncthreads();
        int woff = 0;
        for (int w = 0; w < wave; ++w) woff += wtot[w];
        int ex = woff + incl - s; // exclusive prefix of this thread's pair
        bpref[2 * tid] = ex;
        bpref[2 * tid + 1] = ex + v0;
        if (tid == 0) bpref[NCHUNK] = L_COMP;
        __syncthreads();
    }

    // (b) rank-select this chunk's 33 pos values (threads 0..32)
    if (tid <= CHUNK) {
        int t = base + tid; // global one-rank (0-indexed)
        int posv = L_FULL;
        if (t < L_COMP) {
            int lo = 0, hi = NCHUNK;
            while (hi - lo > 1) {
                int mid = (lo + hi) >> 1;
                if (bpref[mid] <= t) lo = mid; else hi = mid;
            }
            int lr = t - bpref[lo]; // local rank within segment lo
            const int4* bseg = reinterpret_cast<const int4*>(b) + lo * (SEG / 4);
            int cnt = 0;
#pragma unroll 4
            for (int q = 0; q < SEG / 4; ++q) {
                int4 w = bseg[q];
                if (w.x) { if (cnt == lr) posv = lo * SEG + 4 * q + 0; ++cnt; }
                if (w.y) { if (cnt == lr) posv = lo * SEG + 4 * q + 1; ++cnt; }
                if (w.z) { if (cnt == lr) posv = lo * SEG + 4 * q + 2; ++cnt; }
                if (w.w) { if (cnt == lr) posv = lo * SEG + 4 * q + 3; ++cnt; }
            }
        }
        spos[tid] = posv;
    }
    __syncthreads();

    // (c) final scan of chunk c with true init from Hbuf; ranged broadcast writes
    {
        const v4f* x4 = reinterpret_cast<const v4f*>(x) + (size_t)base * (DCH / 4) + tid;
        v4f* out4 = reinterpret_cast<v4f*>(out) + tid;
        v4f h = reinterpret_cast<const v4f*>(Hbuf)[c * (DCH / 4) + tid];
        int f0 = spos[0];
        for (int ib = 0; ib < CHUNK; ib += 8) {
            v4f xv[8];
            float pv[8];
            int fe[8];
#pragma unroll
            for (int j = 0; j < 8; ++j) {
                xv[j] = x4[(ib + j) * (DCH / 4)];
                pv[j] = clipp(p[base + ib + j]); // uniform -> scalar
                fe[j] = spos[ib + j + 1];        // LDS
            }
#pragma unroll
            for (int j = 0; j < 8; ++j) {
                float a = 1.0f - pv[j];
                h = a * h + pv[j] * xv[j];
                for (int f = f0; f < fe[j]; ++f) {
                    out4[(size_t)f * (DCH / 4)] = h;
                }
                f0 = fe[j];
            }
        }
    }
}

extern "C" void kernel_launch(void* const* d_in, const int* in_sizes, int n_in,
                              void* d_out, int out_size, void* d_ws, size_t ws_size,
                              hipStream_t stream) {
    const float* x = (const float*)d_in[0];
    const float* p = (const float*)d_in[1];
    const int* b = (const int*)d_in[2];
    float* out = (float*)d_out;

    char* ws = (char*)d_ws;
    float* Abuf = (float*)ws;                  // NCHUNK floats (2 KiB)
    int* bsum = (int*)(ws + 4096);             // NCHUNK ints (2 KiB)
    float* Bbuf = (float*)(ws + 8192);         // NCHUNK*DCH floats (2 MiB), 16B aligned
    float* Hbuf = Bbuf + (size_t)NCHUNK * DCH; // NCHUNK*DCH floats (2 MiB)

    chunk_kernel<<<NCHUNK, 256, 0, stream>>>(x, p, b, Bbuf, Abuf, bsum);
    interchunk_kernel<<<4, 64, 0, stream>>>(Bbuf, Abuf, Hbuf);
    dechunk_kernel<<<NCHUNK, 256, 0, stream>>>(x, p, b, out, Hbuf, bsum);
}

// Round 9
// 212.131 us; speedup vs baseline: 6.9018x; 1.1074x over previous
//
#include <hip/hip_runtime.h>

// EMA chunked scan + inverse-gather broadcast for DeChunkLayer (R9).
// R9 = R6 (best, 225.9 us) + ONE variable: nontemporal OUT stores.
//
// Evidence so far: R8 showed the redundant replay is ~free (removing it +
// adding a boundary cost +9 us). R7 calibration: fixed harness ~129 us =>
// R6 kernel portion ~97 us vs ~30 us traffic model; K2 (~75 us) carries the
// inefficiency. Hypothesis: 128 MiB of cached out-stores write-allocate
// through L2/L3, evicting L3-warm x and L2-resident Bbuf that K2 reads
// concurrently. nt stores bypass that churn. Loads stay CACHED (R5's
// regression was nt x-loads forcing an HBM re-fetch).
//
// x: (1, 16384, 1024) f32, p_selected: (16384,) f32, b: (1, 32768) i32
// out: (1, 32768, 1024) f32
// z_t = (1-p_t) z_{t-1} + p_t x_t  (p clipped to [1e-4, 1-1e-4])
// out[f] = z[t] for f in [pos[t], pos[t+1])
//
// K1: per-chunk local scan -> Bbuf/Abuf; per-segment b popcount -> bsum.
// K2: per-block redundant interchunk replay (L2/L3 Bbuf) + pos rank-select
//     + final scan + ranged broadcast writes (nontemporal).

#define DCH 1024
#define L_COMP 16384
#define L_FULL 32768
#define CHUNK 32
#define NCHUNK (L_COMP / CHUNK)   // 512
#define SEG (L_FULL / NCHUNK)     // 64 b-elements per block
#define EPSV 1e-4f

typedef float v4f __attribute__((ext_vector_type(4)));

__device__ __forceinline__ float clipp(float p) {
    p = fmaxf(p, EPSV);
    return fminf(p, 1.0f - EPSV);
}

// ---- K1: chunk-local scan (zero init) -> Bbuf[c], Abuf[c]; b segment sums
__global__ __launch_bounds__(256, 2) void chunk_kernel(
    const float* __restrict__ x, const float* __restrict__ p,
    const int* __restrict__ b,
    float* __restrict__ Bbuf, float* __restrict__ Abuf, int* __restrict__ bsum) {
    const int c = blockIdx.x;
    const int tid = threadIdx.x;
    const int lane = tid & 63;
    const int wave = tid >> 6;
    const int base = c * CHUNK;

    const v4f* x4 = reinterpret_cast<const v4f*>(x) + (size_t)base * (DCH / 4) + tid;
    v4f h = (v4f)0.f;
    float aprod = 1.0f;
    for (int ib = 0; ib < CHUNK; ib += 8) {
        v4f xv[8];
        float pv[8];
#pragma unroll
        for (int j = 0; j < 8; ++j) {
            xv[j] = x4[(ib + j) * (DCH / 4)];
            pv[j] = clipp(p[base + ib + j]); // uniform -> scalar load
        }
#pragma unroll
        for (int j = 0; j < 8; ++j) {
            float a = 1.0f - pv[j];
            h = a * h + pv[j] * xv[j];
            aprod *= a;
        }
    }
    reinterpret_cast<v4f*>(Bbuf)[c * (DCH / 4) + tid] = h;
    if (tid == 0) Abuf[c] = aprod;
    if (wave == 0) {
        int v = b[c * SEG + lane];
        int s = v;
#pragma unroll
        for (int off = 1; off < 64; off <<= 1) s += __shfl_xor(s, off, 64);
        if (lane == 0) bsum[c] = s;
    }
}

// ---- K2: bpref scan + rank-select pos + redundant interchunk + final scan/write
__global__ __launch_bounds__(256, 2) void dechunk_kernel(
    const float* __restrict__ x, const float* __restrict__ p,
    const int* __restrict__ b, float* __restrict__ out,
    const float* __restrict__ Bbuf, const float* __restrict__ Abuf,
    const int* __restrict__ bsum) {
    const int c = blockIdx.x;
    const int tid = threadIdx.x;
    const int lane = tid & 63;
    const int wave = tid >> 6;
    const int base = c * CHUNK;

    __shared__ int bpref[NCHUNK + 1];
    __shared__ int spos[CHUNK + 1];
    __shared__ int wtot[4];

    // (a) block-local exclusive prefix over the 512 segment sums
    {
        int v0 = bsum[2 * tid];
        int v1 = bsum[2 * tid + 1];
        int s = v0 + v1;
        int incl = s;
#pragma unroll
        for (int off = 1; off < 64; off <<= 1) {
            int n = __shfl_up(incl, off, 64);
            if (lane >= off) incl += n;
        }
        if (lane == 63) wtot[wave] = incl;
        __syncthreads();
        int woff = 0;
        for (int w = 0; w < wave; ++w) woff += wtot[w];
        int ex = woff + incl - s; // exclusive prefix of this thread's pair
        bpref[2 * tid] = ex;
        bpref[2 * tid + 1] = ex + v0;
        if (tid == 0) bpref[NCHUNK] = L_COMP;
        __syncthreads();
    }

    // (b) rank-select this chunk's 33 pos values (threads 0..32)
    if (tid <= CHUNK) {
        int t = base + tid; // global one-rank (0-indexed)
        int posv = L_FULL;
        if (t < L_COMP) {
            int lo = 0, hi = NCHUNK;
            while (hi - lo > 1) {
                int mid = (lo + hi) >> 1;
                if (bpref[mid] <= t) lo = mid; else hi = mid;
            }
            int lr = t - bpref[lo]; // local rank within segment lo
            const int4* bseg = reinterpret_cast<const int4*>(b) + lo * (SEG / 4);
            int cnt = 0;
#pragma unroll 4
            for (int q = 0; q < SEG / 4; ++q) {
                int4 w = bseg[q];
                if (w.x) { if (cnt == lr) posv = lo * SEG + 4 * q + 0; ++cnt; }
                if (w.y) { if (cnt == lr) posv = lo * SEG + 4 * q + 1; ++cnt; }
                if (w.z) { if (cnt == lr) posv = lo * SEG + 4 * q + 2; ++cnt; }
                if (w.w) { if (cnt == lr) posv = lo * SEG + 4 * q + 3; ++cnt; }
            }
        }
        spos[tid] = posv;
    }

    // (c) redundant interchunk replay: h = state before chunk c (4 channels/thread)
    v4f h = (v4f)0.f;
    {
        const v4f* B4 = reinterpret_cast<const v4f*>(Bbuf) + tid;
        int k = 0;
        for (; k + 16 <= c; k += 16) {
            v4f bv[16];
            float av[16];
#pragma unroll
            for (int j = 0; j < 16; ++j) {
                bv[j] = B4[(k + j) * (DCH / 4)];
                av[j] = Abuf[k + j]; // uniform -> scalar load
            }
#pragma unroll
            for (int j = 0; j < 16; ++j)
                h = av[j] * h + bv[j];
        }
        for (; k < c; ++k) {
            v4f bv = B4[k * (DCH / 4)];
            h = Abuf[k] * h + bv;
        }
    }
    __syncthreads();

    // (d) final scan of chunk c with true init; ranged broadcast writes (NT)
    {
        const v4f* x4 = reinterpret_cast<const v4f*>(x) + (size_t)base * (DCH / 4) + tid;
        v4f* out4 = reinterpret_cast<v4f*>(out) + tid;
        int f0 = spos[0];
        for (int ib = 0; ib < CHUNK; ib += 8) {
            v4f xv[8];
            float pv[8];
            int fe[8];
#pragma unroll
            for (int j = 0; j < 8; ++j) {
                xv[j] = x4[(ib + j) * (DCH / 4)];   // cached: L3-warm x
                pv[j] = clipp(p[base + ib + j]);    // uniform -> scalar
                fe[j] = spos[ib + j + 1];           // LDS
            }
#pragma unroll
            for (int j = 0; j < 8; ++j) {
                float a = 1.0f - pv[j];
                h = a * h + pv[j] * xv[j];
                for (int f = f0; f < fe[j]; ++f) {
                    __builtin_nontemporal_store(h, &out4[(size_t)f * (DCH / 4)]);
                }
                f0 = fe[j];
            }
        }
    }
}

extern "C" void kernel_launch(void* const* d_in, const int* in_sizes, int n_in,
                              void* d_out, int out_size, void* d_ws, size_t ws_size,
                              hipStream_t stream) {
    const float* x = (const float*)d_in[0];
    const float* p = (const float*)d_in[1];
    const int* b = (const int*)d_in[2];
    float* out = (float*)d_out;

    char* ws = (char*)d_ws;
    float* Abuf = (float*)ws;                  // NCHUNK floats (2 KiB)
    int* bsum = (int*)(ws + 4096);             // NCHUNK ints (2 KiB)
    float* Bbuf = (float*)(ws + 8192);         // NCHUNK*DCH floats (2 MiB), 16B aligned

    chunk_kernel<<<NCHUNK, 256, 0, stream>>>(x, p, b, Bbuf, Abuf, bsum);
    dechunk_kernel<<<NCHUNK, 256, 0, stream>>>(x, p, b, out, Bbuf, Abuf, bsum);
}